// Round 3
// baseline (2679.284 us; speedup 1.0000x reference)
//
#include <hip/hip_runtime.h>
#include <math.h>

// GCN generator: B=8, N=F=128. One block/batch, 1024 threads (16 waves),
// 128 sequential steps in-kernel, f16-pair (hi + lo*2^-11) MFMA 16x16x32.
// Round 3: W pre-split into registers (static!), degree reduction folded into
// the G-normalize pass (rowsums + O(1) corrections), row/col-i substitution
// merged into the normalize pass. 6 barriers/step (was 8).

#define NN 128
#define SP 136
#define KSC 2048.0f
#define KINV 4.8828125e-4f

typedef _Float16 f16;
typedef _Float16 f16x8 __attribute__((ext_vector_type(8)));
typedef _Float16 f16x4 __attribute__((ext_vector_type(4)));
typedef float f32x4 __attribute__((ext_vector_type(4)));

__device__ __forceinline__ f32x4 mm(f16x8 a, f16x8 b, f32x4 c) {
    return __builtin_amdgcn_mfma_f32_16x16x32_f16(a, b, c, 0, 0, 0);
}

__global__ __launch_bounds__(1024)
void gcn_gen_kernel(const float* __restrict__ gx,
                    const float* __restrict__ gW,
                    const float* __restrict__ gb,
                    float* __restrict__ gout)
{
    extern __shared__ char lds_raw[];
    f16* G_hi = (f16*)lds_raw;                 // [128][136] adjacency hi
    f16* G_lo = G_hi + NN*SP;                  // adjacency lo (scaled 2048)
    f16* X_hi = G_lo + NN*SP;                  // xT [f][n] (also y [n][f])
    f16* X_lo = X_hi + NN*SP;
    float* s_prob = (float*)(X_lo + NN*SP);    // [128]
    float* s_d    = s_prob + NN;               // [128] rsqrt degrees
    float* s_zrow = s_d + NN;                  // [128] pivot z row
    float* s_ssq  = s_zrow + NN;               // [4][128] ssq partials by wc
    float* s_pdt  = s_ssq + 4*NN;              // [4][128] zdot partials by wc
    float* s_rows = s_pdt + 4*NN;              // [2][128] rowsums (ping-pong)
    float* s_tmp  = s_rows + 2*NN;             // [2] masked prob-sum partials

    const int b = blockIdx.x;
    const int t = threadIdx.x;
    const int lane = t & 63;
    const int w = t >> 6;                      // wave 0..15
    const int wr = w >> 2, wc = w & 3;         // wave grid 4x4 (32x32/wave)
    const int lrow = lane & 15;
    const int lgrp = lane >> 4;
    const int j8 = t >> 3, s8 = t & 7;         // 8 threads per matrix row

    const float* xb = gx + (size_t)b*NN*NN;
    float* outb = gout + (size_t)b*NN*NN;

    const float bias0 = gb[wc*32 + lrow];
    const float bias1 = gb[wc*32 + 16 + lrow];

    // ---- W -> registers as mm2 B-fragments (f16 pairs), one-time ----
    f16x8 Wh[4][2], Wl[4][2];
    #pragma unroll
    for (int ks = 0; ks < 4; ++ks)
    #pragma unroll
    for (int ct = 0; ct < 2; ++ct) {
        const int col = wc*32 + ct*16 + lrow;
        #pragma unroll
        for (int r = 0; r < 8; ++r) {
            float wv = gW[(ks*32 + lgrp*8 + r)*NN + col];
            f16 h = (f16)wv;
            Wh[ks][ct][r] = h;
            Wl[ks][ct][r] = (f16)((wv - (float)h)*KSC);
        }
    }

    // ---- init: G = I pairs, out = eye, X = split(x^T), vectors ----
    #pragma unroll
    for (int q = 0; q < 16; ++q) {
        int idx = q*1024 + t;
        int r = idx >> 7, c = idx & 127;
        float e = (r == c) ? 1.f : 0.f;
        G_hi[r*SP + c] = (f16)e;
        G_lo[r*SP + c] = (f16)0.f;
        outb[idx] = e;
        float v = xb[idx];
        f16 h = (f16)v;
        X_hi[c*SP + r] = h;
        X_lo[c*SP + r] = (f16)((v - (float)h)*KSC);
    }
    if (t < NN) {
        s_rows[t]      = 1.f;                  // rowsum(G=I) both buffers
        s_rows[NN + t] = 1.f;
        s_d[t] = 1.f/sqrtf(2.f + 1e-8f);
        s_prob[t] = 0.f;
    }
    if (t < 2) s_tmp[t] = 0.f;
    __syncthreads();

    for (int i = 0; i < NN; ++i) {
        const int piv = (i + 1) & 127;

        // ---- (a) merged: substitute row/col i with prob, out writes,
        //      G = d.*(G+I).*d, rowsum accumulation ----
        {
            const int arow = j8, c0 = s8*16;
            const int rb = (i + 1) & 1, wb2 = i & 1;
            const float sum_tmp = s_tmp[0] + s_tmp[1];
            const float d_piv = 1.f/sqrtf(s_rows[rb*NN + i] + 1.f + sum_tmp + 1e-8f);
            const float dr = (arow == i) ? d_piv : s_d[arow];
            float dc[16];
            #pragma unroll
            for (int q = 0; q < 4; ++q)
                *(float4*)(dc + 4*q) = *(const float4*)(s_d + c0 + 4*q);
            #pragma unroll
            for (int e = 0; e < 16; ++e)
                if (c0 + e == i) dc[e] = d_piv;

            f16x8* ph = (f16x8*)(G_hi + arow*SP + c0);
            f16x8* pl = (f16x8*)(G_lo + arow*SP + c0);
            f16x8 h0 = ph[0], h1 = ph[1], l0 = pl[0], l1 = pl[1];
            float g[16];
            #pragma unroll
            for (int e = 0; e < 8; ++e) {
                g[e]     = (float)h0[e] + (float)l0[e]*KINV;
                g[8 + e] = (float)h1[e] + (float)l1[e]*KINV;
            }
            if (i > 0) {
                if (arow == i) {
                    #pragma unroll
                    for (int e = 0; e < 16; ++e) {
                        int c = c0 + e;
                        if (c < i) {
                            float pv = s_prob[c];
                            g[e] = pv;
                            outb[i*NN + c] = pv;
                        }
                    }
                } else if (arow < i && c0 <= i && i < c0 + 16) {
                    float pv = s_prob[arow];
                    #pragma unroll
                    for (int e = 0; e < 16; ++e)
                        if (c0 + e == i) g[e] = pv;
                    outb[arow*NN + i] = pv;
                }
            }
            float rsum = 0.f;
            f16x8 nh0, nh1, nl0, nl1;
            #pragma unroll
            for (int e = 0; e < 16; ++e) {
                int c = c0 + e;
                float v = (g[e] + ((c == arow) ? 1.f : 0.f)) * dr * dc[e];
                rsum += v;
                f16 hh = (f16)v;
                f16 ll = (f16)((v - (float)hh)*KSC);
                if (e < 8) { nh0[e] = hh; nl0[e] = ll; }
                else       { nh1[e-8] = hh; nl1[e-8] = ll; }
            }
            ph[0] = nh0; ph[1] = nh1;
            pl[0] = nl0; pl[1] = nl1;
            rsum += __shfl_xor(rsum, 1);
            rsum += __shfl_xor(rsum, 2);
            rsum += __shfl_xor(rsum, 4);
            if (s8 == 0) s_rows[wb2*NN + arow] = rsum;
        }
        __syncthreads();

        // ---- (b) mm1: y = G @ x ----
        f32x4 acc[2][2], cc[2][2];
        #pragma unroll
        for (int rt = 0; rt < 2; ++rt)
            #pragma unroll
            for (int ct = 0; ct < 2; ++ct) {
                acc[rt][ct] = (f32x4){0.f,0.f,0.f,0.f};
                cc[rt][ct]  = (f32x4){0.f,0.f,0.f,0.f};
            }
        #pragma unroll
        for (int ks = 0; ks < 4; ++ks) {
            const int ko = ks*32 + lgrp*8;
            f16x8 Bh[2], Bl[2];
            #pragma unroll
            for (int ct = 0; ct < 2; ++ct) {
                int col = wc*32 + ct*16 + lrow;
                Bh[ct] = *(const f16x8*)(X_hi + col*SP + ko);
                Bl[ct] = *(const f16x8*)(X_lo + col*SP + ko);
            }
            #pragma unroll
            for (int rt = 0; rt < 2; ++rt) {
                int row = wr*32 + rt*16 + lrow;
                f16x8 Ah = *(const f16x8*)(G_hi + row*SP + ko);
                f16x8 Al = *(const f16x8*)(G_lo + row*SP + ko);
                #pragma unroll
                for (int ct = 0; ct < 2; ++ct) {
                    acc[rt][ct] = mm(Ah, Bh[ct], acc[rt][ct]);
                    cc[rt][ct]  = mm(Ah, Bl[ct], cc[rt][ct]);
                    cc[rt][ct]  = mm(Al, Bh[ct], cc[rt][ct]);
                }
            }
        }
        __syncthreads();

        // ---- (c) y -> X buffers, row-major [n][f] pairs ----
        #pragma unroll
        for (int rt = 0; rt < 2; ++rt)
        #pragma unroll
        for (int ct = 0; ct < 2; ++ct) {
            int col = wc*32 + ct*16 + lrow;
            #pragma unroll
            for (int q = 0; q < 4; ++q) {
                int row = wr*32 + rt*16 + lgrp*4 + q;
                float v = acc[rt][ct][q] + cc[rt][ct][q]*KINV;
                f16 h = (f16)v;
                X_hi[row*SP + col] = h;
                X_lo[row*SP + col] = (f16)((v - (float)h)*KSC);
            }
        }
        __syncthreads();

        // ---- (d) mm2: z = y @ W (W fragments in registers) + epilogue ----
        #pragma unroll
        for (int rt = 0; rt < 2; ++rt)
            #pragma unroll
            for (int ct = 0; ct < 2; ++ct) {
                acc[rt][ct] = (f32x4){0.f,0.f,0.f,0.f};
                cc[rt][ct]  = (f32x4){0.f,0.f,0.f,0.f};
            }
        #pragma unroll
        for (int ks = 0; ks < 4; ++ks) {
            const int ko = ks*32 + lgrp*8;
            #pragma unroll
            for (int rt = 0; rt < 2; ++rt) {
                int row = wr*32 + rt*16 + lrow;
                f16x8 Ah = *(const f16x8*)(X_hi + row*SP + ko);
                f16x8 Al = *(const f16x8*)(X_lo + row*SP + ko);
                #pragma unroll
                for (int ct = 0; ct < 2; ++ct) {
                    acc[rt][ct] = mm(Ah, Wh[ks][ct], acc[rt][ct]);
                    cc[rt][ct]  = mm(Ah, Wl[ks][ct], cc[rt][ct]);
                    cc[rt][ct]  = mm(Al, Wh[ks][ct], cc[rt][ct]);
                }
            }
        }
        float z[2][2][4];
        #pragma unroll
        for (int rt = 0; rt < 2; ++rt)
        #pragma unroll
        for (int ct = 0; ct < 2; ++ct)
        #pragma unroll
        for (int q = 0; q < 4; ++q)
            z[rt][ct][q] = fmaxf(acc[rt][ct][q] + cc[rt][ct][q]*KINV
                                 + (ct ? bias1 : bias0), 0.f);
        {
            float ss[8];
            #pragma unroll
            for (int k = 0; k < 8; ++k) {
                float a = z[k>>2][0][k&3], c2 = z[k>>2][1][k&3];
                ss[k] = a*a + c2*c2;
            }
            #pragma unroll
            for (int k = 0; k < 8; ++k) {
                ss[k] += __shfl_xor(ss[k], 1);
                ss[k] += __shfl_xor(ss[k], 2);
                ss[k] += __shfl_xor(ss[k], 4);
                ss[k] += __shfl_xor(ss[k], 8);
            }
            if (lrow == 0) {
                #pragma unroll
                for (int k = 0; k < 8; ++k) {
                    int row = wr*32 + (k>>2)*16 + lgrp*4 + (k&3);
                    s_ssq[wc*NN + row] = ss[k];
                }
            }
        }
        if (wr == (piv>>5) && lgrp == ((piv>>2)&3)) {
            int prt = (piv>>4)&1, pq = piv&3;
            s_zrow[wc*32 + lrow]      = z[prt][0][pq];
            s_zrow[wc*32 + 16 + lrow] = z[prt][1][pq];
        }
        __syncthreads();

        // ---- (e) normalize + write new x (xT pairs) + zdot partials ----
        {
            float dv[8];
            #pragma unroll
            for (int k = 0; k < 8; ++k) {
                int row = wr*32 + (k>>2)*16 + lgrp*4 + (k&3);
                float sq = s_ssq[row] + s_ssq[NN+row] + s_ssq[2*NN+row] + s_ssq[3*NN+row];
                dv[k] = (i == 0) ? 1.f : 1.f/(sqrtf(sq) + 1e-8f);
            }
            #pragma unroll
            for (int rt = 0; rt < 2; ++rt)
            #pragma unroll
            for (int ct = 0; ct < 2; ++ct) {
                int col = wc*32 + ct*16 + lrow;
                int rowb = wr*32 + rt*16 + lgrp*4;
                f16x4 hv, lv;
                #pragma unroll
                for (int q = 0; q < 4; ++q) {
                    float v = z[rt][ct][q] * dv[rt*4+q];
                    f16 h = (f16)v;
                    hv[q] = h;
                    lv[q] = (f16)((v - (float)h)*KSC);
                }
                *(f16x4*)(X_hi + col*SP + rowb) = hv;
                *(f16x4*)(X_lo + col*SP + rowb) = lv;
            }
            float zr0 = s_zrow[wc*32 + lrow];
            float zr1 = s_zrow[wc*32 + 16 + lrow];
            float pd[8];
            #pragma unroll
            for (int k = 0; k < 8; ++k)
                pd[k] = z[k>>2][0][k&3]*zr0 + z[k>>2][1][k&3]*zr1;
            #pragma unroll
            for (int k = 0; k < 8; ++k) {
                pd[k] += __shfl_xor(pd[k], 1);
                pd[k] += __shfl_xor(pd[k], 2);
                pd[k] += __shfl_xor(pd[k], 4);
                pd[k] += __shfl_xor(pd[k], 8);
            }
            if (lrow == 0) {
                #pragma unroll
                for (int k = 0; k < 8; ++k) {
                    int row = wr*32 + (k>>2)*16 + lgrp*4 + (k&3);
                    s_pdt[wc*NN + row] = pd[k];
                }
            }
        }
        __syncthreads();

        // ---- (f) probs + next-step degrees (t < 128 only) ----
        if (t < NN) {
            const int pn = i + 1;              // un-wrapped pivot
            float zd  = s_pdt[t] + s_pdt[NN+t] + s_pdt[2*NN+t] + s_pdt[3*NN+t];
            float sqj = s_ssq[t] + s_ssq[NN+t] + s_ssq[2*NN+t] + s_ssq[3*NN+t];
            float sqp = s_ssq[piv] + s_ssq[NN+piv] + s_ssq[2*NN+piv] + s_ssq[3*NN+piv];
            float dj = 1.f, dp = 1.f;
            if (i > 0) {
                dj = 1.f/(sqrtf(sqj) + 1e-8f);
                dp = 1.f/(sqrtf(sqp) + 1e-8f);
            }
            float sc = 0.5f * zd * dj * dp;
            float pv = 1.f/(1.f + expf(-sc));
            s_prob[t] = pv;
            float corr = (t < pn) ? pv : 0.f;
            s_d[t] = 1.f/sqrtf(s_rows[(i&1)*NN + t] + 1.f + corr + 1e-8f);
            float m = corr;
            m += __shfl_xor(m, 1);
            m += __shfl_xor(m, 2);
            m += __shfl_xor(m, 4);
            m += __shfl_xor(m, 8);
            m += __shfl_xor(m, 16);
            m += __shfl_xor(m, 32);
            if ((t & 63) == 0) s_tmp[t >> 6] = m;
        }
        __syncthreads();
    }
}

extern "C" void kernel_launch(void* const* d_in, const int* in_sizes, int n_in,
                              void* d_out, int out_size, void* d_ws, size_t ws_size,
                              hipStream_t stream) {
    const float* x  = (const float*)d_in[0];
    const float* W  = (const float*)d_in[1];
    const float* bb = (const float*)d_in[2];
    float* out = (float*)d_out;

    const size_t shmem = (size_t)(4*NN*SP)*sizeof(f16)
                       + (size_t)(3*NN + 8*NN + 2*NN + 2)*sizeof(float);
    hipFuncSetAttribute((const void*)gcn_gen_kernel,
                        hipFuncAttributeMaxDynamicSharedMemorySize, (int)shmem);
    gcn_gen_kernel<<<8, 1024, shmem, stream>>>(x, W, bb, out);
}

// Round 4
// 1642.311 us; speedup vs baseline: 1.6314x; 1.6314x over previous
//
#include <hip/hip_runtime.h>
#include <math.h>

// GCN generator: B=8, N=F=128. One block/batch, 1024 threads (16 waves),
// 128 sequential steps in-kernel. Round 4: pure-f16 storage (fp32 MFMA
// accumulate + fp32 epilogue), W pre-split into registers (32 VGPRs),
// __launch_bounds__(1024,4) to unlock 128 VGPRs (round-3 spill fix).
// 6 barriers/step.

#define NN 128
#define SP 136

typedef _Float16 f16;
typedef _Float16 f16x8 __attribute__((ext_vector_type(8)));
typedef _Float16 f16x4 __attribute__((ext_vector_type(4)));
typedef float f32x4 __attribute__((ext_vector_type(4)));

__device__ __forceinline__ f32x4 mm(f16x8 a, f16x8 b, f32x4 c) {
    return __builtin_amdgcn_mfma_f32_16x16x32_f16(a, b, c, 0, 0, 0);
}

__global__ __launch_bounds__(1024, 4)
void gcn_gen_kernel(const float* __restrict__ gx,
                    const float* __restrict__ gW,
                    const float* __restrict__ gb,
                    float* __restrict__ gout)
{
    extern __shared__ char lds_raw[];
    f16* G = (f16*)lds_raw;                    // [128][136] normalized adjacency
    f16* X = G + NN*SP;                        // xT [f][n] (also y [n][f])
    float* s_prob = (float*)(X + NN*SP);       // [128]
    float* s_d    = s_prob + NN;               // [128] rsqrt degrees
    float* s_zrow = s_d + NN;                  // [128] pivot z row
    float* s_ssq  = s_zrow + NN;               // [4][128] ssq partials by wc
    float* s_pdt  = s_ssq + 4*NN;              // [4][128] zdot partials by wc
    float* s_rows = s_pdt + 4*NN;              // [2][128] rowsums (ping-pong)
    float* s_tmp  = s_rows + 2*NN;             // [2] masked prob-sum partials

    const int b = blockIdx.x;
    const int t = threadIdx.x;
    const int lane = t & 63;
    const int w = t >> 6;                      // wave 0..15
    const int wr = w >> 2, wc = w & 3;         // wave grid 4x4 (32x32/wave)
    const int lrow = lane & 15;
    const int lgrp = lane >> 4;
    const int j8 = t >> 3, s8 = t & 7;         // 8 threads per matrix row

    const float* xb = gx + (size_t)b*NN*NN;
    float* outb = gout + (size_t)b*NN*NN;

    const float bias0 = gb[wc*32 + lrow];
    const float bias1 = gb[wc*32 + 16 + lrow];

    // ---- W -> registers as mm2 B-fragments (pure f16), one-time ----
    f16x8 Wh[4][2];
    #pragma unroll
    for (int ks = 0; ks < 4; ++ks)
    #pragma unroll
    for (int ct = 0; ct < 2; ++ct) {
        const int col = wc*32 + ct*16 + lrow;
        #pragma unroll
        for (int r = 0; r < 8; ++r)
            Wh[ks][ct][r] = (f16)gW[(ks*32 + lgrp*8 + r)*NN + col];
    }

    // ---- init: G = I, out = eye, X = f16(x^T), vectors ----
    #pragma unroll
    for (int q = 0; q < 16; ++q) {
        int idx = q*1024 + t;
        int r = idx >> 7, c = idx & 127;
        float e = (r == c) ? 1.f : 0.f;
        G[r*SP + c] = (f16)e;
        outb[idx] = e;
        X[c*SP + r] = (f16)xb[idx];
    }
    if (t < NN) {
        s_rows[t]      = 1.f;                  // rowsum(G=I) both buffers
        s_rows[NN + t] = 1.f;
        s_d[t] = 1.f/sqrtf(2.f + 1e-8f);
        s_prob[t] = 0.f;
    }
    if (t < 2) s_tmp[t] = 0.f;
    __syncthreads();

    for (int i = 0; i < NN; ++i) {
        const int piv = (i + 1) & 127;

        // ---- (a) merged: substitute row/col i, out writes,
        //      G = d.*(G+I).*d, rowsum accumulation ----
        {
            const int arow = j8, c0 = s8*16;
            const int rb = (i + 1) & 1, wb2 = i & 1;
            const float sum_tmp = s_tmp[0] + s_tmp[1];
            const float d_piv = 1.f/sqrtf(s_rows[rb*NN + i] + 1.f + sum_tmp + 1e-8f);
            const float dr = (arow == i) ? d_piv : s_d[arow];
            float dc[16];
            #pragma unroll
            for (int q = 0; q < 4; ++q)
                *(float4*)(dc + 4*q) = *(const float4*)(s_d + c0 + 4*q);
            #pragma unroll
            for (int e = 0; e < 16; ++e)
                if (c0 + e == i) dc[e] = d_piv;

            f16x8* ph = (f16x8*)(G + arow*SP + c0);
            f16x8 h0 = ph[0], h1 = ph[1];
            float g[16];
            #pragma unroll
            for (int e = 0; e < 8; ++e) {
                g[e]     = (float)h0[e];
                g[8 + e] = (float)h1[e];
            }
            if (i > 0) {
                if (arow == i) {
                    #pragma unroll
                    for (int e = 0; e < 16; ++e) {
                        int c = c0 + e;
                        if (c < i) {
                            float pv = s_prob[c];
                            g[e] = pv;
                            outb[i*NN + c] = pv;
                        }
                    }
                } else if (arow < i && c0 <= i && i < c0 + 16) {
                    float pv = s_prob[arow];
                    #pragma unroll
                    for (int e = 0; e < 16; ++e)
                        if (c0 + e == i) g[e] = pv;
                    outb[arow*NN + i] = pv;
                }
            }
            float rsum = 0.f;
            f16x8 nh0, nh1;
            #pragma unroll
            for (int e = 0; e < 16; ++e) {
                int c = c0 + e;
                float v = (g[e] + ((c == arow) ? 1.f : 0.f)) * dr * dc[e];
                rsum += v;
                f16 hh = (f16)v;
                if (e < 8) nh0[e] = hh; else nh1[e-8] = hh;
            }
            ph[0] = nh0; ph[1] = nh1;
            rsum += __shfl_xor(rsum, 1);
            rsum += __shfl_xor(rsum, 2);
            rsum += __shfl_xor(rsum, 4);
            if (s8 == 0) s_rows[wb2*NN + arow] = rsum;
        }
        __syncthreads();

        // ---- (b) mm1: y = G @ x ----
        f32x4 acc[2][2];
        #pragma unroll
        for (int rt = 0; rt < 2; ++rt)
            #pragma unroll
            for (int ct = 0; ct < 2; ++ct)
                acc[rt][ct] = (f32x4){0.f,0.f,0.f,0.f};
        #pragma unroll
        for (int ks = 0; ks < 4; ++ks) {
            const int ko = ks*32 + lgrp*8;
            f16x8 Bh[2];
            #pragma unroll
            for (int ct = 0; ct < 2; ++ct) {
                int col = wc*32 + ct*16 + lrow;
                Bh[ct] = *(const f16x8*)(X + col*SP + ko);
            }
            #pragma unroll
            for (int rt = 0; rt < 2; ++rt) {
                int row = wr*32 + rt*16 + lrow;
                f16x8 Ah = *(const f16x8*)(G + row*SP + ko);
                #pragma unroll
                for (int ct = 0; ct < 2; ++ct)
                    acc[rt][ct] = mm(Ah, Bh[ct], acc[rt][ct]);
            }
        }
        __syncthreads();

        // ---- (c) y -> X buffer, row-major [n][f] ----
        #pragma unroll
        for (int rt = 0; rt < 2; ++rt)
        #pragma unroll
        for (int ct = 0; ct < 2; ++ct) {
            int col = wc*32 + ct*16 + lrow;
            #pragma unroll
            for (int q = 0; q < 4; ++q) {
                int row = wr*32 + rt*16 + lgrp*4 + q;
                X[row*SP + col] = (f16)acc[rt][ct][q];
            }
        }
        __syncthreads();

        // ---- (d) mm2: z = y @ W (W in registers) + epilogue ----
        #pragma unroll
        for (int rt = 0; rt < 2; ++rt)
            #pragma unroll
            for (int ct = 0; ct < 2; ++ct)
                acc[rt][ct] = (f32x4){0.f,0.f,0.f,0.f};
        #pragma unroll
        for (int ks = 0; ks < 4; ++ks) {
            const int ko = ks*32 + lgrp*8;
            #pragma unroll
            for (int rt = 0; rt < 2; ++rt) {
                int row = wr*32 + rt*16 + lrow;
                f16x8 Ah = *(const f16x8*)(X + row*SP + ko);
                #pragma unroll
                for (int ct = 0; ct < 2; ++ct)
                    acc[rt][ct] = mm(Ah, Wh[ks][ct], acc[rt][ct]);
            }
        }
        float z[2][2][4];
        #pragma unroll
        for (int rt = 0; rt < 2; ++rt)
        #pragma unroll
        for (int ct = 0; ct < 2; ++ct)
        #pragma unroll
        for (int q = 0; q < 4; ++q)
            z[rt][ct][q] = fmaxf(acc[rt][ct][q] + (ct ? bias1 : bias0), 0.f);
        {
            float ss[8];
            #pragma unroll
            for (int k = 0; k < 8; ++k) {
                float a = z[k>>2][0][k&3], c2 = z[k>>2][1][k&3];
                ss[k] = a*a + c2*c2;
            }
            #pragma unroll
            for (int k = 0; k < 8; ++k) {
                ss[k] += __shfl_xor(ss[k], 1);
                ss[k] += __shfl_xor(ss[k], 2);
                ss[k] += __shfl_xor(ss[k], 4);
                ss[k] += __shfl_xor(ss[k], 8);
            }
            if (lrow == 0) {
                #pragma unroll
                for (int k = 0; k < 8; ++k) {
                    int row = wr*32 + (k>>2)*16 + lgrp*4 + (k&3);
                    s_ssq[wc*NN + row] = ss[k];
                }
            }
        }
        if (wr == (piv>>5) && lgrp == ((piv>>2)&3)) {
            int prt = (piv>>4)&1, pq = piv&3;
            s_zrow[wc*32 + lrow]      = z[prt][0][pq];
            s_zrow[wc*32 + 16 + lrow] = z[prt][1][pq];
        }
        __syncthreads();

        // ---- (e) normalize + write new x (xT) + zdot partials ----
        {
            float dv[8];
            #pragma unroll
            for (int k = 0; k < 8; ++k) {
                int row = wr*32 + (k>>2)*16 + lgrp*4 + (k&3);
                float sq = s_ssq[row] + s_ssq[NN+row] + s_ssq[2*NN+row] + s_ssq[3*NN+row];
                dv[k] = (i == 0) ? 1.f : 1.f/(sqrtf(sq) + 1e-8f);
            }
            #pragma unroll
            for (int rt = 0; rt < 2; ++rt)
            #pragma unroll
            for (int ct = 0; ct < 2; ++ct) {
                int col = wc*32 + ct*16 + lrow;
                int rowb = wr*32 + rt*16 + lgrp*4;
                f16x4 hv;
                #pragma unroll
                for (int q = 0; q < 4; ++q)
                    hv[q] = (f16)(z[rt][ct][q] * dv[rt*4+q]);
                *(f16x4*)(X + col*SP + rowb) = hv;
            }
            float zr0 = s_zrow[wc*32 + lrow];
            float zr1 = s_zrow[wc*32 + 16 + lrow];
            float pd[8];
            #pragma unroll
            for (int k = 0; k < 8; ++k)
                pd[k] = z[k>>2][0][k&3]*zr0 + z[k>>2][1][k&3]*zr1;
            #pragma unroll
            for (int k = 0; k < 8; ++k) {
                pd[k] += __shfl_xor(pd[k], 1);
                pd[k] += __shfl_xor(pd[k], 2);
                pd[k] += __shfl_xor(pd[k], 4);
                pd[k] += __shfl_xor(pd[k], 8);
            }
            if (lrow == 0) {
                #pragma unroll
                for (int k = 0; k < 8; ++k) {
                    int row = wr*32 + (k>>2)*16 + lgrp*4 + (k&3);
                    s_pdt[wc*NN + row] = pd[k];
                }
            }
        }
        __syncthreads();

        // ---- (f) probs + next-step degrees (t < 128 only) ----
        if (t < NN) {
            const int pn = i + 1;
            float zd  = s_pdt[t] + s_pdt[NN+t] + s_pdt[2*NN+t] + s_pdt[3*NN+t];
            float sqj = s_ssq[t] + s_ssq[NN+t] + s_ssq[2*NN+t] + s_ssq[3*NN+t];
            float sqp = s_ssq[piv] + s_ssq[NN+piv] + s_ssq[2*NN+piv] + s_ssq[3*NN+piv];
            float dj = 1.f, dp = 1.f;
            if (i > 0) {
                dj = 1.f/(sqrtf(sqj) + 1e-8f);
                dp = 1.f/(sqrtf(sqp) + 1e-8f);
            }
            float sc = 0.5f * zd * dj * dp;
            float pv = 1.f/(1.f + expf(-sc));
            s_prob[t] = pv;
            float corr = (t < pn) ? pv : 0.f;
            s_d[t] = 1.f/sqrtf(s_rows[(i&1)*NN + t] + 1.f + corr + 1e-8f);
            float m = corr;
            m += __shfl_xor(m, 1);
            m += __shfl_xor(m, 2);
            m += __shfl_xor(m, 4);
            m += __shfl_xor(m, 8);
            m += __shfl_xor(m, 16);
            m += __shfl_xor(m, 32);
            if ((t & 63) == 0) s_tmp[t >> 6] = m;
        }
        __syncthreads();
    }
}

extern "C" void kernel_launch(void* const* d_in, const int* in_sizes, int n_in,
                              void* d_out, int out_size, void* d_ws, size_t ws_size,
                              hipStream_t stream) {
    const float* x  = (const float*)d_in[0];
    const float* W  = (const float*)d_in[1];
    const float* bb = (const float*)d_in[2];
    float* out = (float*)d_out;

    const size_t shmem = (size_t)(2*NN*SP)*sizeof(f16)
                       + (size_t)(3*NN + 8*NN + 2*NN + 2)*sizeof(float);
    hipFuncSetAttribute((const void*)gcn_gen_kernel,
                        hipFuncAttributeMaxDynamicSharedMemorySize, (int)shmem);
    gcn_gen_kernel<<<8, 1024, shmem, stream>>>(x, W, bb, out);
}